// Round 1
// baseline (89.201 us; speedup 1.0000x reference)
//
#include <hip/hip_runtime.h>
#include <math.h>

// CrossAttentionModule: 3D neighborhood attention (NATTEN-style clamped window)
// B=1, C=64, D=64, H=64, W=8, HEADS=8, hd=8, K=(3,3,3), dil=1.
// Pipeline: instancenorm(skip,up) -> q,k = skip_n @ w_qk ; v = up_n @ w_v
//        -> 27-neighbor attention with relative position bias -> @ w_proj.
// All fp32. ws holds stats + q,k,v,a_pre (position-major [p][c]).

#define PD 64
#define PH 64
#define PW 8
#define PTOT (PD*PH*PW)   // 32768
#define NC 64
#define NHEADS 8
#define HD 8
#define ATT_SCALE 0.35355339059327373f  // 1/sqrt(8)

// ws layout in floats
#define WS_STATS 0                  // [tensor(0=skip,1=up)*64 + c]*2 : mean, rstd
#define WS_Q 1024
#define WS_K (WS_Q + PTOT*NC)
#define WS_V (WS_K + PTOT*NC)
#define WS_A (WS_V + PTOT*NC)
// total = 1024 + 4*2097152 floats = ~33.6 MB

__global__ __launch_bounds__(256) void k_stats(const float* __restrict__ skip,
                                               const float* __restrict__ up,
                                               float* __restrict__ ws) {
  int bid = blockIdx.x;                       // 0..127 : tensor*64 + c
  const float* src = (bid < 64) ? skip : up;
  int c = bid & 63;
  const float4* base = (const float4*)(src + (size_t)c * PTOT);
  float s1 = 0.f, s2 = 0.f;
  for (int i = threadIdx.x; i < PTOT/4; i += 256) {
    float4 v = base[i];
    s1 += v.x + v.y + v.z + v.w;
    s2 += v.x*v.x + v.y*v.y + v.z*v.z + v.w*v.w;
  }
  #pragma unroll
  for (int off = 32; off; off >>= 1) {
    s1 += __shfl_down(s1, off);
    s2 += __shfl_down(s2, off);
  }
  __shared__ float red[8];
  int wid = threadIdx.x >> 6;
  if ((threadIdx.x & 63) == 0) { red[wid*2] = s1; red[wid*2+1] = s2; }
  __syncthreads();
  if (threadIdx.x == 0) {
    float a = 0.f, b = 0.f;
    #pragma unroll
    for (int w2 = 0; w2 < 4; w2++) { a += red[w2*2]; b += red[w2*2+1]; }
    float mean = a / (float)PTOT;
    float var  = b / (float)PTOT - mean*mean;     // population var (ddof=0)
    ws[WS_STATS + bid*2]     = mean;
    ws[WS_STATS + bid*2 + 1] = rsqrtf(var + 1e-5f);
  }
}

// Fused inorm + QK/V projection. Block: 64 positions, 6 waves.
// Waves 0..3: 32 qk-columns each (128 total, from skip_n).
// Waves 4..5: 32 v-columns each  (64 total, from up_n).
// W accessed at wave-uniform addresses -> scalar loads (SGPR operands).
__global__ __launch_bounds__(384) void k_qkv(const float* __restrict__ skip,
                                             const float* __restrict__ up,
                                             const float* __restrict__ w_qk,
                                             const float* __restrict__ b_qk,
                                             const float* __restrict__ w_v,
                                             const float* __restrict__ b_v,
                                             float* __restrict__ ws) {
  __shared__ float As[NC][65];   // pad 65: column read As[c][lane] conflict-free
  __shared__ float Au[NC][65];
  const float* stats = ws + WS_STATS;
  int p0 = blockIdx.x * 64;
  for (int idx = threadIdx.x; idx < NC*64; idx += 384) {
    int c = idx >> 6, pl = idx & 63;
    float xs = skip[(size_t)c*PTOT + p0 + pl];
    float xu = up  [(size_t)c*PTOT + p0 + pl];
    As[c][pl] = (xs - stats[c*2])       * stats[c*2+1];
    Au[c][pl] = (xu - stats[128 + c*2]) * stats[128 + c*2+1];
  }
  __syncthreads();
  int wid  = threadIdx.x >> 6;
  int lane = threadIdx.x & 63;
  int p = p0 + lane;
  float acc[32];
  if (wid < 4) {
    int jb = __builtin_amdgcn_readfirstlane(wid * 32);   // qk column base (0..96)
    #pragma unroll
    for (int jj = 0; jj < 32; jj++) acc[jj] = b_qk[jb + jj];
    for (int c = 0; c < NC; c++) {
      float a = As[c][lane];
      #pragma unroll
      for (int jj = 0; jj < 32; jj++)
        acc[jj] = fmaf(a, w_qk[c*128 + jb + jj], acc[jj]);
    }
    float* dst = ws + ((jb < 64) ? WS_Q : WS_K) + (size_t)p*NC + (jb & 63);
    #pragma unroll
    for (int g = 0; g < 8; g++) {
      float4 o = make_float4(acc[4*g], acc[4*g+1], acc[4*g+2], acc[4*g+3]);
      *(float4*)(dst + 4*g) = o;
    }
  } else {
    int jb = __builtin_amdgcn_readfirstlane((wid - 4) * 32); // v column base
    #pragma unroll
    for (int jj = 0; jj < 32; jj++) acc[jj] = b_v[jb + jj];
    for (int c = 0; c < NC; c++) {
      float a = Au[c][lane];
      #pragma unroll
      for (int jj = 0; jj < 32; jj++)
        acc[jj] = fmaf(a, w_v[c*64 + jb + jj], acc[jj]);
    }
    float* dst = ws + WS_V + (size_t)p*NC + jb;
    #pragma unroll
    for (int g = 0; g < 8; g++) {
      float4 o = make_float4(acc[4*g], acc[4*g+1], acc[4*g+2], acc[4*g+3]);
      *(float4*)(dst + 4*g) = o;
    }
  }
}

// Attention. One wave = one (d,h) row: 8 w-positions x 8 heads = 64 lanes.
// Each lane does a full 27-neighbor attention for its (position, head):
// no cross-lane ops at all. k/v reads are contiguous ~2KB per neighbor/wave.
__global__ __launch_bounds__(256) void k_attn(const float* __restrict__ rpb,
                                              float* __restrict__ ws) {
  __shared__ float rpb_s[NHEADS * 125];
  for (int i = threadIdx.x; i < NHEADS*125; i += 256) rpb_s[i] = rpb[i];
  __syncthreads();

  int wid  = threadIdx.x >> 6;
  int lane = threadIdx.x & 63;
  int job = blockIdx.x * 4 + wid;           // 0..4095
  int d = job >> 6;                         // 0..63
  int h = job & 63;                         // 0..63
  int w    = lane >> 3;                     // 0..7
  int head = lane & 7;                      // 0..7

  int sd = min(max(d - 1, 0), PD - 3);
  int sh = min(max(h - 1, 0), PH - 3);
  int sw = min(max(w - 1, 0), PW - 3);

  int pdre[3], phre[3], pwre[3], brd[3], brh[3], brw[3];
  #pragma unroll
  for (int j = 0; j < 3; j++) {
    pdre[j] = (sd + j) * (PH * PW);
    phre[j] = (sh + j) * PW;
    pwre[j] = sw + j;
    brd[j] = (sd + j - d + 2) * 25;
    brh[j] = (sh + j - h + 2) * 5;
    brw[j] = (sw + j - w + 2);
  }
  int p = (d * PH + h) * PW + w;

  const float* qb = ws + WS_Q + (size_t)p * NC + head * HD;
  float4 q0 = *(const float4*)qb;
  float4 q1 = *(const float4*)(qb + 4);
  const float* kb = ws + WS_K;
  const float* vb = ws + WS_V;
  int hb = head * 125;

  float lg[27];
  float m = -1e30f;
  #pragma unroll
  for (int jd = 0; jd < 3; jd++)
  #pragma unroll
  for (int jh = 0; jh < 3; jh++)
  #pragma unroll
  for (int jw = 0; jw < 3; jw++) {
    int n = (jd * 3 + jh) * 3 + jw;
    int pn = pdre[jd] + phre[jh] + pwre[jw];
    const float4* kp = (const float4*)(kb + (size_t)pn * NC + head * HD);
    float4 k0 = kp[0], k1 = kp[1];
    float dot = q0.x*k0.x + q0.y*k0.y + q0.z*k0.z + q0.w*k0.w
              + q1.x*k1.x + q1.y*k1.y + q1.z*k1.z + q1.w*k1.w;
    float l = dot * ATT_SCALE + rpb_s[hb + brd[jd] + brh[jh] + brw[jw]];
    lg[n] = l;
    m = fmaxf(m, l);
  }
  float den = 0.f;
  #pragma unroll
  for (int n = 0; n < 27; n++) {
    float e = __expf(lg[n] - m);
    lg[n] = e;
    den += e;
  }
  float inv = 1.f / den;

  float4 a0 = make_float4(0,0,0,0), a1 = make_float4(0,0,0,0);
  #pragma unroll
  for (int jd = 0; jd < 3; jd++)
  #pragma unroll
  for (int jh = 0; jh < 3; jh++)
  #pragma unroll
  for (int jw = 0; jw < 3; jw++) {
    int n = (jd * 3 + jh) * 3 + jw;
    int pn = pdre[jd] + phre[jh] + pwre[jw];
    const float4* vp = (const float4*)(vb + (size_t)pn * NC + head * HD);
    float4 v0 = vp[0], v1 = vp[1];
    float wgt = lg[n];
    a0.x = fmaf(wgt, v0.x, a0.x); a0.y = fmaf(wgt, v0.y, a0.y);
    a0.z = fmaf(wgt, v0.z, a0.z); a0.w = fmaf(wgt, v0.w, a0.w);
    a1.x = fmaf(wgt, v1.x, a1.x); a1.y = fmaf(wgt, v1.y, a1.y);
    a1.z = fmaf(wgt, v1.z, a1.z); a1.w = fmaf(wgt, v1.w, a1.w);
  }
  a0.x *= inv; a0.y *= inv; a0.z *= inv; a0.w *= inv;
  a1.x *= inv; a1.y *= inv; a1.z *= inv; a1.w *= inv;

  float* ab = ws + WS_A + (size_t)p * NC + head * HD;
  *(float4*)ab       = a0;
  *(float4*)(ab + 4) = a1;
}

// Output projection. Block: 64 positions, 4 waves x 16 output channels.
// Stores out[c][p] -> fully coalesced (lane = position).
__global__ __launch_bounds__(256) void k_proj(const float* __restrict__ w_proj,
                                              const float* __restrict__ b_proj,
                                              const float* __restrict__ ws_c,
                                              float* __restrict__ out) {
  __shared__ float A[64][65];
  int p0 = blockIdx.x * 64;
  const float* apre = ws_c + WS_A;
  for (int idx = threadIdx.x; idx < 64*NC; idx += 256) {
    int pl = idx >> 6, c = idx & 63;
    A[pl][c] = apre[(size_t)(p0 + pl) * NC + c];  // coalesced (c fast)
  }
  __syncthreads();
  int wid  = threadIdx.x >> 6;
  int lane = threadIdx.x & 63;
  int jb = __builtin_amdgcn_readfirstlane(wid * 16);
  float acc[16];
  #pragma unroll
  for (int jj = 0; jj < 16; jj++) acc[jj] = b_proj[jb + jj];
  for (int c = 0; c < NC; c++) {
    float a = A[lane][c];   // bank = (lane+c)%32 -> 2-way (free)
    #pragma unroll
    for (int jj = 0; jj < 16; jj++)
      acc[jj] = fmaf(a, w_proj[c*64 + jb + jj], acc[jj]);
  }
  #pragma unroll
  for (int jj = 0; jj < 16; jj++)
    out[(size_t)(jb + jj) * PTOT + p0 + lane] = acc[jj];
}

extern "C" void kernel_launch(void* const* d_in, const int* in_sizes, int n_in,
                              void* d_out, int out_size, void* d_ws, size_t ws_size,
                              hipStream_t stream) {
  const float* skip = (const float*)d_in[0];
  const float* up   = (const float*)d_in[1];
  const float* w_qk = (const float*)d_in[2];
  const float* b_qk = (const float*)d_in[3];
  const float* w_v  = (const float*)d_in[4];
  const float* b_v  = (const float*)d_in[5];
  const float* w_pr = (const float*)d_in[6];
  const float* b_pr = (const float*)d_in[7];
  const float* rpb  = (const float*)d_in[8];
  float* ws  = (float*)d_ws;
  float* out = (float*)d_out;

  k_stats<<<128, 256, 0, stream>>>(skip, up, ws);
  k_qkv<<<PTOT/64, 384, 0, stream>>>(skip, up, w_qk, b_qk, w_v, b_v, ws);
  k_attn<<<(PD*PH)/4, 256, 0, stream>>>(rpb, ws);
  k_proj<<<PTOT/64, 256, 0, stream>>>(w_pr, b_pr, ws, out);
}

// Round 2
// 67.653 us; speedup vs baseline: 1.3185x; 1.3185x over previous
//
#include <hip/hip_runtime.h>
#include <math.h>

// CrossAttentionModule: 3D neighborhood attention (NATTEN-style clamped window)
// B=1, C=64, D=64, H=64, W=8, HEADS=8, hd=8, K=(3,3,3), dil=1. All fp32.
//
// R2 restructure: LDS-free wave-job projections (64 pos x 16 cols per wave),
// norm fused into the QKV projection via precomputed per-channel mean/rstd,
// attention output stored transposed [c][p] so k_proj reads coalesced.

#define PD 64
#define PH 64
#define PW 8
#define PTOT (PD*PH*PW)   // 32768
#define NC 64
#define NHEADS 8
#define HD 8
#define ATT_SCALE 0.35355339059327373f  // 1/sqrt(8)

// ws layout (floats)
#define WS_PART 0                      // 256 jobs x {s1,s2} = 512
#define WS_MR   512                    // 128 tc x {mean,rstd} = 256
#define WS_Q    1024
#define WS_K    (WS_Q + PTOT*NC)
#define WS_V    (WS_K + PTOT*NC)
#define WS_A    (WS_V + PTOT*NC)       // attention output, [c][p] layout

// Partial sums: 256 blocks, each does half of one (tensor,channel).
__global__ __launch_bounds__(512) void k_stats(const float* __restrict__ skip,
                                               const float* __restrict__ up,
                                               float* __restrict__ ws) {
  int job = blockIdx.x;               // 0..255
  int tc = job >> 1, half = job & 1;
  const float* src = (tc < 64) ? (skip + (size_t)tc * PTOT)
                               : (up + (size_t)(tc - 64) * PTOT);
  const float4* b4 = (const float4*)(src + half * (PTOT / 2));
  float s1 = 0.f, s2 = 0.f;
  #pragma unroll
  for (int it = 0; it < 8; it++) {
    float4 v = b4[it * 512 + threadIdx.x];
    s1 += v.x + v.y + v.z + v.w;
    s2 += v.x*v.x + v.y*v.y + v.z*v.z + v.w*v.w;
  }
  #pragma unroll
  for (int off = 32; off; off >>= 1) {
    s1 += __shfl_down(s1, off);
    s2 += __shfl_down(s2, off);
  }
  __shared__ float red[16];
  int wid = threadIdx.x >> 6;
  if ((threadIdx.x & 63) == 0) { red[wid*2] = s1; red[wid*2+1] = s2; }
  __syncthreads();
  if (threadIdx.x == 0) {
    float a = 0.f, b = 0.f;
    #pragma unroll
    for (int w2 = 0; w2 < 8; w2++) { a += red[w2*2]; b += red[w2*2+1]; }
    ws[WS_PART + job*2]     = a;
    ws[WS_PART + job*2 + 1] = b;
  }
}

__global__ void k_fin(float* __restrict__ ws) {
  int tc = threadIdx.x;               // 128 threads
  if (tc < 128) {
    float s1 = ws[WS_PART + (tc*2)*2]   + ws[WS_PART + (tc*2+1)*2];
    float s2 = ws[WS_PART + (tc*2)*2+1] + ws[WS_PART + (tc*2+1)*2+1];
    float mean = s1 / (float)PTOT;
    float var  = s2 / (float)PTOT - mean*mean;
    ws[WS_MR + tc*2]     = mean;
    ws[WS_MR + tc*2 + 1] = rsqrtf(var + 1e-5f);
  }
}

// Fused inorm + QK/V projection. One wave = 64 positions x 16 columns.
// grid (512, 3), block 256 (4 waves): cs = blockIdx.y*4+wid in 0..11.
// cs 0..7 -> qk columns cs*16 (from skip_n); cs 8..11 -> v columns (from up_n).
// x loads: global, coalesced 256B/instr (vmcnt). Weights: wave-uniform s_load.
__global__ __launch_bounds__(256) void k_qkv(const float* __restrict__ skip,
                                             const float* __restrict__ up,
                                             const float* __restrict__ w_qk,
                                             const float* __restrict__ b_qk,
                                             const float* __restrict__ w_v,
                                             const float* __restrict__ b_v,
                                             float* __restrict__ ws) {
  int lane = threadIdx.x & 63;
  int wid  = threadIdx.x >> 6;
  int cs = __builtin_amdgcn_readfirstlane(blockIdx.y * 4 + wid);  // 0..11
  int p  = blockIdx.x * 64 + lane;
  const float* mr = ws + WS_MR;
  float acc[16];
  if (cs < 8) {
    int jb = cs * 16;                 // qk column base, uniform
    #pragma unroll
    for (int j = 0; j < 16; j++) acc[j] = b_qk[jb + j];
    const float* w = w_qk + jb;
    #pragma unroll 8
    for (int c = 0; c < NC; c++) {
      float a = (skip[(size_t)c * PTOT + p] - mr[c*2]) * mr[c*2+1];
      #pragma unroll
      for (int j = 0; j < 16; j++)
        acc[j] = fmaf(a, w[c*128 + j], acc[j]);
    }
    float* dst = ws + ((jb < 64) ? WS_Q : WS_K) + (size_t)p * NC + (jb & 63);
    #pragma unroll
    for (int g = 0; g < 4; g++)
      *(float4*)(dst + 4*g) = make_float4(acc[4*g], acc[4*g+1], acc[4*g+2], acc[4*g+3]);
  } else {
    int jb = (cs - 8) * 16;           // v column base, uniform
    #pragma unroll
    for (int j = 0; j < 16; j++) acc[j] = b_v[jb + j];
    const float* w = w_v + jb;
    #pragma unroll 8
    for (int c = 0; c < NC; c++) {
      float a = (up[(size_t)c * PTOT + p] - mr[128 + c*2]) * mr[128 + c*2+1];
      #pragma unroll
      for (int j = 0; j < 16; j++)
        acc[j] = fmaf(a, w[c*64 + j], acc[j]);
    }
    float* dst = ws + WS_V + (size_t)p * NC + jb;
    #pragma unroll
    for (int g = 0; g < 4; g++)
      *(float4*)(dst + 4*g) = make_float4(acc[4*g], acc[4*g+1], acc[4*g+2], acc[4*g+3]);
  }
}

// Attention. One wave = one (d,h) row: 8 w-positions x 8 heads = 64 lanes.
// Per-lane 27-neighbor softmax-attention, no cross-lane ops.
// Output written TRANSPOSED to [c][p] for coalesced k_proj reads.
__global__ __launch_bounds__(256) void k_attn(const float* __restrict__ rpb,
                                              float* __restrict__ ws) {
  __shared__ float rpb_s[NHEADS * 125];
  for (int i = threadIdx.x; i < NHEADS*125; i += 256) rpb_s[i] = rpb[i];
  __syncthreads();

  int wid  = threadIdx.x >> 6;
  int lane = threadIdx.x & 63;
  int job = blockIdx.x * 4 + wid;           // 0..4095
  int d = job >> 6;
  int h = job & 63;
  int w    = lane >> 3;                     // 0..7
  int head = lane & 7;                      // 0..7

  int sd = min(max(d - 1, 0), PD - 3);
  int sh = min(max(h - 1, 0), PH - 3);
  int sw = min(max(w - 1, 0), PW - 3);

  int pdre[3], phre[3], pwre[3], brd[3], brh[3], brw[3];
  #pragma unroll
  for (int j = 0; j < 3; j++) {
    pdre[j] = (sd + j) * (PH * PW);
    phre[j] = (sh + j) * PW;
    pwre[j] = sw + j;
    brd[j] = (sd + j - d + 2) * 25;
    brh[j] = (sh + j - h + 2) * 5;
    brw[j] = (sw + j - w + 2);
  }
  int p = (d * PH + h) * PW + w;

  const float* qb = ws + WS_Q + (size_t)p * NC + head * HD;
  float4 q0 = *(const float4*)qb;
  float4 q1 = *(const float4*)(qb + 4);
  const float* kb = ws + WS_K;
  const float* vb = ws + WS_V;
  int hb = head * 125;

  float lg[27];
  float m = -1e30f;
  #pragma unroll
  for (int jd = 0; jd < 3; jd++)
  #pragma unroll
  for (int jh = 0; jh < 3; jh++)
  #pragma unroll
  for (int jw = 0; jw < 3; jw++) {
    int n = (jd * 3 + jh) * 3 + jw;
    int pn = pdre[jd] + phre[jh] + pwre[jw];
    const float4* kp = (const float4*)(kb + (size_t)pn * NC + head * HD);
    float4 k0 = kp[0], k1 = kp[1];
    float dot = q0.x*k0.x + q0.y*k0.y + q0.z*k0.z + q0.w*k0.w
              + q1.x*k1.x + q1.y*k1.y + q1.z*k1.z + q1.w*k1.w;
    float l = dot * ATT_SCALE + rpb_s[hb + brd[jd] + brh[jh] + brw[jw]];
    lg[n] = l;
    m = fmaxf(m, l);
  }
  float den = 0.f;
  #pragma unroll
  for (int n = 0; n < 27; n++) {
    float e = __expf(lg[n] - m);
    lg[n] = e;
    den += e;
  }
  float inv = 1.f / den;

  float4 a0 = make_float4(0,0,0,0), a1 = make_float4(0,0,0,0);
  #pragma unroll
  for (int jd = 0; jd < 3; jd++)
  #pragma unroll
  for (int jh = 0; jh < 3; jh++)
  #pragma unroll
  for (int jw = 0; jw < 3; jw++) {
    int n = (jd * 3 + jh) * 3 + jw;
    int pn = pdre[jd] + phre[jh] + pwre[jw];
    const float4* vp = (const float4*)(vb + (size_t)pn * NC + head * HD);
    float4 v0 = vp[0], v1 = vp[1];
    float wgt = lg[n];
    a0.x = fmaf(wgt, v0.x, a0.x); a0.y = fmaf(wgt, v0.y, a0.y);
    a0.z = fmaf(wgt, v0.z, a0.z); a0.w = fmaf(wgt, v0.w, a0.w);
    a1.x = fmaf(wgt, v1.x, a1.x); a1.y = fmaf(wgt, v1.y, a1.y);
    a1.z = fmaf(wgt, v1.z, a1.z); a1.w = fmaf(wgt, v1.w, a1.w);
  }
  float o[8] = {a0.x*inv, a0.y*inv, a0.z*inv, a0.w*inv,
                a1.x*inv, a1.y*inv, a1.z*inv, a1.w*inv};
  float* ab = ws + WS_A;
  #pragma unroll
  for (int i = 0; i < 8; i++)
    ab[(size_t)(head * 8 + i) * PTOT + p] = o[i];   // transposed store [c][p]
}

// Output projection, LDS-free wave-jobs like k_qkv.
// Block 256 = 4 waves x 16 cols; reads ws_A [c][p] coalesced; stores coalesced.
__global__ __launch_bounds__(256) void k_proj(const float* __restrict__ w_proj,
                                              const float* __restrict__ b_proj,
                                              const float* __restrict__ ws_c,
                                              float* __restrict__ out) {
  int lane = threadIdx.x & 63;
  int jb = __builtin_amdgcn_readfirstlane((threadIdx.x >> 6) * 16);
  int p = blockIdx.x * 64 + lane;
  const float* A = ws_c + WS_A;
  float acc[16];
  #pragma unroll
  for (int j = 0; j < 16; j++) acc[j] = b_proj[jb + j];
  #pragma unroll 8
  for (int c = 0; c < NC; c++) {
    float a = A[(size_t)c * PTOT + p];
    #pragma unroll
    for (int j = 0; j < 16; j++)
      acc[j] = fmaf(a, w_proj[c*64 + jb + j], acc[j]);
  }
  #pragma unroll
  for (int j = 0; j < 16; j++)
    out[(size_t)(jb + j) * PTOT + p] = acc[j];
}

extern "C" void kernel_launch(void* const* d_in, const int* in_sizes, int n_in,
                              void* d_out, int out_size, void* d_ws, size_t ws_size,
                              hipStream_t stream) {
  const float* skip = (const float*)d_in[0];
  const float* up   = (const float*)d_in[1];
  const float* w_qk = (const float*)d_in[2];
  const float* b_qk = (const float*)d_in[3];
  const float* w_v  = (const float*)d_in[4];
  const float* b_v  = (const float*)d_in[5];
  const float* w_pr = (const float*)d_in[6];
  const float* b_pr = (const float*)d_in[7];
  const float* rpb  = (const float*)d_in[8];
  float* ws  = (float*)d_ws;
  float* out = (float*)d_out;

  k_stats<<<256, 512, 0, stream>>>(skip, up, ws);
  k_fin<<<1, 128, 0, stream>>>(ws);
  k_qkv<<<dim3(512, 3), 256, 0, stream>>>(skip, up, w_qk, b_qk, w_v, b_v, ws);
  k_attn<<<(PD*PH)/4, 256, 0, stream>>>(rpb, ws);
  k_proj<<<PTOT/64, 256, 0, stream>>>(w_pr, b_pr, ws, out);
}

// Round 3
// 67.167 us; speedup vs baseline: 1.3280x; 1.0072x over previous
//
#include <hip/hip_runtime.h>
#include <math.h>

// CrossAttentionModule: 3D neighborhood attention (NATTEN-style clamped window)
// B=1, C=64, D=64, H=64, W=8, HEADS=8, hd=8, K=(3,3,3), dil=1. All fp32.
//
// R3: 3-kernel pipeline.
//   k_stats     : per-(tensor,channel) mean/rstd, written directly (no k_fin).
//   k_qkv       : fused inorm + QK/V projection (LDS-free wave-jobs).
//   k_attn_proj : 27-neighbor attention + output projection fused via LDS.

#define PD 64
#define PH 64
#define PW 8
#define PTOT (PD*PH*PW)   // 32768
#define NC 64
#define NHEADS 8
#define HD 8
#define ATT_SCALE 0.35355339059327373f  // 1/sqrt(8)

// ws layout (floats)
#define WS_MR   0                      // 128 tc x {mean,rstd} = 256
#define WS_Q    1024
#define WS_K    (WS_Q + PTOT*NC)
#define WS_V    (WS_K + PTOT*NC)

// One block per (tensor,channel): direct mean/rstd, no second pass.
__global__ __launch_bounds__(1024) void k_stats(const float* __restrict__ skip,
                                                const float* __restrict__ up,
                                                float* __restrict__ ws) {
  int tc = blockIdx.x;                // 0..127
  const float* src = (tc < 64) ? (skip + (size_t)tc * PTOT)
                               : (up + (size_t)(tc - 64) * PTOT);
  const float4* b4 = (const float4*)src;
  float s1 = 0.f, s2 = 0.f;
  #pragma unroll
  for (int it = 0; it < 8; it++) {
    float4 v = b4[it * 1024 + threadIdx.x];
    s1 += v.x + v.y + v.z + v.w;
    s2 += v.x*v.x + v.y*v.y + v.z*v.z + v.w*v.w;
  }
  #pragma unroll
  for (int off = 32; off; off >>= 1) {
    s1 += __shfl_down(s1, off);
    s2 += __shfl_down(s2, off);
  }
  __shared__ float red[32];
  int wid = threadIdx.x >> 6;
  if ((threadIdx.x & 63) == 0) { red[wid*2] = s1; red[wid*2+1] = s2; }
  __syncthreads();
  if (threadIdx.x == 0) {
    float a = 0.f, b = 0.f;
    #pragma unroll
    for (int w2 = 0; w2 < 16; w2++) { a += red[w2*2]; b += red[w2*2+1]; }
    float mean = a / (float)PTOT;
    float var  = b / (float)PTOT - mean*mean;   // population var (ddof=0)
    ws[WS_MR + tc*2]     = mean;
    ws[WS_MR + tc*2 + 1] = rsqrtf(var + 1e-5f);
  }
}

// Fused inorm + QK/V projection. One wave = 64 positions x 16 columns.
// grid (512, 3), block 256 (4 waves): cs = blockIdx.y*4+wid in 0..11.
// cs 0..7 -> qk columns cs*16 (from skip_n); cs 8..11 -> v columns (from up_n).
// x loads: global, coalesced 256B/instr (vmcnt). Weights: wave-uniform s_load.
__global__ __launch_bounds__(256) void k_qkv(const float* __restrict__ skip,
                                             const float* __restrict__ up,
                                             const float* __restrict__ w_qk,
                                             const float* __restrict__ b_qk,
                                             const float* __restrict__ w_v,
                                             const float* __restrict__ b_v,
                                             float* __restrict__ ws) {
  int lane = threadIdx.x & 63;
  int wid  = threadIdx.x >> 6;
  int cs = __builtin_amdgcn_readfirstlane(blockIdx.y * 4 + wid);  // 0..11
  int p  = blockIdx.x * 64 + lane;
  const float* mr = ws + WS_MR;
  float acc[16];
  if (cs < 8) {
    int jb = cs * 16;                 // qk column base, uniform
    #pragma unroll
    for (int j = 0; j < 16; j++) acc[j] = b_qk[jb + j];
    const float* w = w_qk + jb;
    #pragma unroll 8
    for (int c = 0; c < NC; c++) {
      float a = (skip[(size_t)c * PTOT + p] - mr[c*2]) * mr[c*2+1];
      #pragma unroll
      for (int j = 0; j < 16; j++)
        acc[j] = fmaf(a, w[c*128 + j], acc[j]);
    }
    float* dst = ws + ((jb < 64) ? WS_Q : WS_K) + (size_t)p * NC + (jb & 63);
    #pragma unroll
    for (int g = 0; g < 4; g++)
      *(float4*)(dst + 4*g) = make_float4(acc[4*g], acc[4*g+1], acc[4*g+2], acc[4*g+3]);
  } else {
    int jb = (cs - 8) * 16;           // v column base, uniform
    #pragma unroll
    for (int j = 0; j < 16; j++) acc[j] = b_v[jb + j];
    const float* w = w_v + jb;
    #pragma unroll 8
    for (int c = 0; c < NC; c++) {
      float a = (up[(size_t)c * PTOT + p] - mr[128 + c*2]) * mr[128 + c*2+1];
      #pragma unroll
      for (int j = 0; j < 16; j++)
        acc[j] = fmaf(a, w[c*64 + j], acc[j]);
    }
    float* dst = ws + WS_V + (size_t)p * NC + jb;
    #pragma unroll
    for (int g = 0; g < 4; g++)
      *(float4*)(dst + 4*g) = make_float4(acc[4*g], acc[4*g+1], acc[4*g+2], acc[4*g+3]);
  }
}

// Fused attention + output projection.
// Block = 512 threads = 8 waves = 8 consecutive (d,h) rows = 64 contiguous
// positions. Phase 1: per-lane (w,head) 27-neighbor softmax-attention ->
// LDS A[64][65] (scalar writes, conflict-free). Phase 2: per-wave 8 output
// columns over 64 positions; A reads stride-65 conflict-free; w_proj via
// wave-uniform s_loads; coalesced 256B stores.
__global__ __launch_bounds__(512) void k_attn_proj(const float* __restrict__ rpb,
                                                   const float* __restrict__ w_proj,
                                                   const float* __restrict__ b_proj,
                                                   float* __restrict__ ws,
                                                   float* __restrict__ out) {
  __shared__ float A[64][65];
  __shared__ float rpb_s[NHEADS * 125];
  for (int i = threadIdx.x; i < NHEADS*125; i += 512) rpb_s[i] = rpb[i];
  __syncthreads();

  int wid  = threadIdx.x >> 6;
  int lane = threadIdx.x & 63;
  int job = blockIdx.x * 8 + wid;           // 0..4095 (8 consecutive h per block)
  int d = job >> 6;
  int h = job & 63;
  int w    = lane >> 3;                     // 0..7
  int head = lane & 7;                      // 0..7

  int sd = min(max(d - 1, 0), PD - 3);
  int sh = min(max(h - 1, 0), PH - 3);
  int sw = min(max(w - 1, 0), PW - 3);

  int pdre[3], phre[3], pwre[3], brd[3], brh[3], brw[3];
  #pragma unroll
  for (int j = 0; j < 3; j++) {
    pdre[j] = (sd + j) * (PH * PW);
    phre[j] = (sh + j) * PW;
    pwre[j] = sw + j;
    brd[j] = (sd + j - d + 2) * 25;
    brh[j] = (sh + j - h + 2) * 5;
    brw[j] = (sw + j - w + 2);
  }
  int p = (d * PH + h) * PW + w;

  const float* qb = ws + WS_Q + (size_t)p * NC + head * HD;
  float4 q0 = *(const float4*)qb;
  float4 q1 = *(const float4*)(qb + 4);
  const float* kb = ws + WS_K;
  const float* vb = ws + WS_V;
  int hb = head * 125;

  float lg[27];
  float m = -1e30f;
  #pragma unroll
  for (int jd = 0; jd < 3; jd++)
  #pragma unroll
  for (int jh = 0; jh < 3; jh++)
  #pragma unroll
  for (int jw = 0; jw < 3; jw++) {
    int n = (jd * 3 + jh) * 3 + jw;
    int pn = pdre[jd] + phre[jh] + pwre[jw];
    const float4* kp = (const float4*)(kb + (size_t)pn * NC + head * HD);
    float4 k0 = kp[0], k1 = kp[1];
    float dot = q0.x*k0.x + q0.y*k0.y + q0.z*k0.z + q0.w*k0.w
              + q1.x*k1.x + q1.y*k1.y + q1.z*k1.z + q1.w*k1.w;
    float l = dot * ATT_SCALE + rpb_s[hb + brd[jd] + brh[jh] + brw[jw]];
    lg[n] = l;
    m = fmaxf(m, l);
  }
  float den = 0.f;
  #pragma unroll
  for (int n = 0; n < 27; n++) {
    float e = __expf(lg[n] - m);
    lg[n] = e;
    den += e;
  }
  float inv = 1.f / den;

  float4 a0 = make_float4(0,0,0,0), a1 = make_float4(0,0,0,0);
  #pragma unroll
  for (int jd = 0; jd < 3; jd++)
  #pragma unroll
  for (int jh = 0; jh < 3; jh++)
  #pragma unroll
  for (int jw = 0; jw < 3; jw++) {
    int n = (jd * 3 + jh) * 3 + jw;
    int pn = pdre[jd] + phre[jh] + pwre[jw];
    const float4* vp = (const float4*)(vb + (size_t)pn * NC + head * HD);
    float4 v0 = vp[0], v1 = vp[1];
    float wgt = lg[n];
    a0.x = fmaf(wgt, v0.x, a0.x); a0.y = fmaf(wgt, v0.y, a0.y);
    a0.z = fmaf(wgt, v0.z, a0.z); a0.w = fmaf(wgt, v0.w, a0.w);
    a1.x = fmaf(wgt, v1.x, a1.x); a1.y = fmaf(wgt, v1.y, a1.y);
    a1.z = fmaf(wgt, v1.z, a1.z); a1.w = fmaf(wgt, v1.w, a1.w);
  }
  int pl = wid * 8 + w;                // position within block (0..63)
  int cb = head * 8;                   // channel base for this lane
  // bank = (pl + cb + i) % 32 -> 2 lanes/bank: conflict-free
  A[pl][cb + 0] = a0.x * inv;
  A[pl][cb + 1] = a0.y * inv;
  A[pl][cb + 2] = a0.z * inv;
  A[pl][cb + 3] = a0.w * inv;
  A[pl][cb + 4] = a1.x * inv;
  A[pl][cb + 5] = a1.y * inv;
  A[pl][cb + 6] = a1.z * inv;
  A[pl][cb + 7] = a1.w * inv;
  __syncthreads();

  // Phase 2: projection. Wave wid handles columns jb..jb+7 for all 64 pos.
  int jb = __builtin_amdgcn_readfirstlane(wid * 8);
  int p0 = blockIdx.x * 64;
  float acc[8];
  #pragma unroll
  for (int j = 0; j < 8; j++) acc[j] = b_proj[jb + j];
  #pragma unroll 8
  for (int c = 0; c < NC; c++) {
    float a = A[lane][c];              // stride 65: conflict-free
    #pragma unroll
    for (int j = 0; j < 8; j++)
      acc[j] = fmaf(a, w_proj[c*64 + jb + j], acc[j]);
  }
  #pragma unroll
  for (int j = 0; j < 8; j++)
    out[(size_t)(jb + j) * PTOT + p0 + lane] = acc[j];
}

extern "C" void kernel_launch(void* const* d_in, const int* in_sizes, int n_in,
                              void* d_out, int out_size, void* d_ws, size_t ws_size,
                              hipStream_t stream) {
  const float* skip = (const float*)d_in[0];
  const float* up   = (const float*)d_in[1];
  const float* w_qk = (const float*)d_in[2];
  const float* b_qk = (const float*)d_in[3];
  const float* w_v  = (const float*)d_in[4];
  const float* b_v  = (const float*)d_in[5];
  const float* w_pr = (const float*)d_in[6];
  const float* b_pr = (const float*)d_in[7];
  const float* rpb  = (const float*)d_in[8];
  float* ws  = (float*)d_ws;
  float* out = (float*)d_out;

  k_stats<<<128, 1024, 0, stream>>>(skip, up, ws);
  k_qkv<<<dim3(512, 3), 256, 0, stream>>>(skip, up, w_qk, b_qk, w_v, b_v, ws);
  k_attn_proj<<<(PD*PH)/8, 512, 0, stream>>>(rpb, w_pr, b_pr, ws, out);
}

// Round 4
// 67.144 us; speedup vs baseline: 1.3285x; 1.0003x over previous
//
#include <hip/hip_runtime.h>
#include <math.h>

// CrossAttentionModule: 3D neighborhood attention (NATTEN-style clamped window)
// B=1, C=64, D=64, H=64, W=8, HEADS=8, hd=8, K=(3,3,3), dil=1. All fp32.
//
// R4: identical to R3 except k_attn_proj gets an XCD-aware block swizzle:
// bid' = (bid%8)*64 + bid/8 groups each XCD's 64 blocks onto 8 consecutive
// d-slabs, so the 27x K/V re-read (450 MB) is served from the XCD's private
// 4 MB L2 (working set ~2.5 MB) instead of Infinity Cache.

#define PD 64
#define PH 64
#define PW 8
#define PTOT (PD*PH*PW)   // 32768
#define NC 64
#define NHEADS 8
#define HD 8
#define ATT_SCALE 0.35355339059327373f  // 1/sqrt(8)

// ws layout (floats)
#define WS_MR   0                      // 128 tc x {mean,rstd} = 256
#define WS_Q    1024
#define WS_K    (WS_Q + PTOT*NC)
#define WS_V    (WS_K + PTOT*NC)

// One block per (tensor,channel): direct mean/rstd, no second pass.
__global__ __launch_bounds__(1024) void k_stats(const float* __restrict__ skip,
                                                const float* __restrict__ up,
                                                float* __restrict__ ws) {
  int tc = blockIdx.x;                // 0..127
  const float* src = (tc < 64) ? (skip + (size_t)tc * PTOT)
                               : (up + (size_t)(tc - 64) * PTOT);
  const float4* b4 = (const float4*)src;
  float s1 = 0.f, s2 = 0.f;
  #pragma unroll
  for (int it = 0; it < 8; it++) {
    float4 v = b4[it * 1024 + threadIdx.x];
    s1 += v.x + v.y + v.z + v.w;
    s2 += v.x*v.x + v.y*v.y + v.z*v.z + v.w*v.w;
  }
  #pragma unroll
  for (int off = 32; off; off >>= 1) {
    s1 += __shfl_down(s1, off);
    s2 += __shfl_down(s2, off);
  }
  __shared__ float red[32];
  int wid = threadIdx.x >> 6;
  if ((threadIdx.x & 63) == 0) { red[wid*2] = s1; red[wid*2+1] = s2; }
  __syncthreads();
  if (threadIdx.x == 0) {
    float a = 0.f, b = 0.f;
    #pragma unroll
    for (int w2 = 0; w2 < 16; w2++) { a += red[w2*2]; b += red[w2*2+1]; }
    float mean = a / (float)PTOT;
    float var  = b / (float)PTOT - mean*mean;   // population var (ddof=0)
    ws[WS_MR + tc*2]     = mean;
    ws[WS_MR + tc*2 + 1] = rsqrtf(var + 1e-5f);
  }
}

// Fused inorm + QK/V projection. One wave = 64 positions x 16 columns.
// grid (512, 3), block 256 (4 waves): cs = blockIdx.y*4+wid in 0..11.
// cs 0..7 -> qk columns cs*16 (from skip_n); cs 8..11 -> v columns (from up_n).
// x loads: global, coalesced 256B/instr (vmcnt). Weights: wave-uniform s_load.
__global__ __launch_bounds__(256) void k_qkv(const float* __restrict__ skip,
                                             const float* __restrict__ up,
                                             const float* __restrict__ w_qk,
                                             const float* __restrict__ b_qk,
                                             const float* __restrict__ w_v,
                                             const float* __restrict__ b_v,
                                             float* __restrict__ ws) {
  int lane = threadIdx.x & 63;
  int wid  = threadIdx.x >> 6;
  int cs = __builtin_amdgcn_readfirstlane(blockIdx.y * 4 + wid);  // 0..11
  int p  = blockIdx.x * 64 + lane;
  const float* mr = ws + WS_MR;
  float acc[16];
  if (cs < 8) {
    int jb = cs * 16;                 // qk column base, uniform
    #pragma unroll
    for (int j = 0; j < 16; j++) acc[j] = b_qk[jb + j];
    const float* w = w_qk + jb;
    #pragma unroll 8
    for (int c = 0; c < NC; c++) {
      float a = (skip[(size_t)c * PTOT + p] - mr[c*2]) * mr[c*2+1];
      #pragma unroll
      for (int j = 0; j < 16; j++)
        acc[j] = fmaf(a, w[c*128 + j], acc[j]);
    }
    float* dst = ws + ((jb < 64) ? WS_Q : WS_K) + (size_t)p * NC + (jb & 63);
    #pragma unroll
    for (int g = 0; g < 4; g++)
      *(float4*)(dst + 4*g) = make_float4(acc[4*g], acc[4*g+1], acc[4*g+2], acc[4*g+3]);
  } else {
    int jb = (cs - 8) * 16;           // v column base, uniform
    #pragma unroll
    for (int j = 0; j < 16; j++) acc[j] = b_v[jb + j];
    const float* w = w_v + jb;
    #pragma unroll 8
    for (int c = 0; c < NC; c++) {
      float a = (up[(size_t)c * PTOT + p] - mr[128 + c*2]) * mr[128 + c*2+1];
      #pragma unroll
      for (int j = 0; j < 16; j++)
        acc[j] = fmaf(a, w[c*64 + j], acc[j]);
    }
    float* dst = ws + WS_V + (size_t)p * NC + jb;
    #pragma unroll
    for (int g = 0; g < 4; g++)
      *(float4*)(dst + 4*g) = make_float4(acc[4*g], acc[4*g+1], acc[4*g+2], acc[4*g+3]);
  }
}

// Fused attention + output projection, XCD-swizzled.
// Block = 512 threads = 8 waves = 8 consecutive (d,h) rows = 64 contiguous
// positions. Phase 1: per-lane (w,head) 27-neighbor softmax-attention ->
// LDS A[64][65]. Phase 2: per-wave 8 output columns over 64 positions.
__global__ __launch_bounds__(512) void k_attn_proj(const float* __restrict__ rpb,
                                                   const float* __restrict__ w_proj,
                                                   const float* __restrict__ b_proj,
                                                   float* __restrict__ ws,
                                                   float* __restrict__ out) {
  __shared__ float A[64][65];
  __shared__ float rpb_s[NHEADS * 125];
  for (int i = threadIdx.x; i < NHEADS*125; i += 512) rpb_s[i] = rpb[i];
  __syncthreads();

  // XCD swizzle: dispatch maps bid%8 -> XCD. Give XCD k blocks covering
  // d in [8k, 8k+8): bid' = (bid%8)*64 + bid/8 (bijection, 512 = 8*64).
  int bid = ((blockIdx.x & 7) << 6) + (blockIdx.x >> 3);

  int wid  = threadIdx.x >> 6;
  int lane = threadIdx.x & 63;
  int job = bid * 8 + wid;                  // 0..4095
  int d = job >> 6;
  int h = job & 63;
  int w    = lane >> 3;                     // 0..7
  int head = lane & 7;                      // 0..7

  int sd = min(max(d - 1, 0), PD - 3);
  int sh = min(max(h - 1, 0), PH - 3);
  int sw = min(max(w - 1, 0), PW - 3);

  int pdre[3], phre[3], pwre[3], brd[3], brh[3], brw[3];
  #pragma unroll
  for (int j = 0; j < 3; j++) {
    pdre[j] = (sd + j) * (PH * PW);
    phre[j] = (sh + j) * PW;
    pwre[j] = sw + j;
    brd[j] = (sd + j - d + 2) * 25;
    brh[j] = (sh + j - h + 2) * 5;
    brw[j] = (sw + j - w + 2);
  }
  int p = (d * PH + h) * PW + w;

  const float* qb = ws + WS_Q + (size_t)p * NC + head * HD;
  float4 q0 = *(const float4*)qb;
  float4 q1 = *(const float4*)(qb + 4);
  const float* kb = ws + WS_K;
  const float* vb = ws + WS_V;
  int hb = head * 125;

  float lg[27];
  float m = -1e30f;
  #pragma unroll
  for (int jd = 0; jd < 3; jd++)
  #pragma unroll
  for (int jh = 0; jh < 3; jh++)
  #pragma unroll
  for (int jw = 0; jw < 3; jw++) {
    int n = (jd * 3 + jh) * 3 + jw;
    int pn = pdre[jd] + phre[jh] + pwre[jw];
    const float4* kp = (const float4*)(kb + (size_t)pn * NC + head * HD);
    float4 k0 = kp[0], k1 = kp[1];
    float dot = q0.x*k0.x + q0.y*k0.y + q0.z*k0.z + q0.w*k0.w
              + q1.x*k1.x + q1.y*k1.y + q1.z*k1.z + q1.w*k1.w;
    float l = dot * ATT_SCALE + rpb_s[hb + brd[jd] + brh[jh] + brw[jw]];
    lg[n] = l;
    m = fmaxf(m, l);
  }
  float den = 0.f;
  #pragma unroll
  for (int n = 0; n < 27; n++) {
    float e = __expf(lg[n] - m);
    lg[n] = e;
    den += e;
  }
  float inv = 1.f / den;

  float4 a0 = make_float4(0,0,0,0), a1 = make_float4(0,0,0,0);
  #pragma unroll
  for (int jd = 0; jd < 3; jd++)
  #pragma unroll
  for (int jh = 0; jh < 3; jh++)
  #pragma unroll
  for (int jw = 0; jw < 3; jw++) {
    int n = (jd * 3 + jh) * 3 + jw;
    int pn = pdre[jd] + phre[jh] + pwre[jw];
    const float4* vp = (const float4*)(vb + (size_t)pn * NC + head * HD);
    float4 v0 = vp[0], v1 = vp[1];
    float wgt = lg[n];
    a0.x = fmaf(wgt, v0.x, a0.x); a0.y = fmaf(wgt, v0.y, a0.y);
    a0.z = fmaf(wgt, v0.z, a0.z); a0.w = fmaf(wgt, v0.w, a0.w);
    a1.x = fmaf(wgt, v1.x, a1.x); a1.y = fmaf(wgt, v1.y, a1.y);
    a1.z = fmaf(wgt, v1.z, a1.z); a1.w = fmaf(wgt, v1.w, a1.w);
  }
  int pl = wid * 8 + w;                // position within block (0..63)
  int cb = head * 8;                   // channel base for this lane
  A[pl][cb + 0] = a0.x * inv;
  A[pl][cb + 1] = a0.y * inv;
  A[pl][cb + 2] = a0.z * inv;
  A[pl][cb + 3] = a0.w * inv;
  A[pl][cb + 4] = a1.x * inv;
  A[pl][cb + 5] = a1.y * inv;
  A[pl][cb + 6] = a1.z * inv;
  A[pl][cb + 7] = a1.w * inv;
  __syncthreads();

  // Phase 2: projection. Wave wid handles columns jb..jb+7 for all 64 pos.
  int jb = __builtin_amdgcn_readfirstlane(wid * 8);
  int p0 = bid * 64;
  float acc[8];
  #pragma unroll
  for (int j = 0; j < 8; j++) acc[j] = b_proj[jb + j];
  #pragma unroll 8
  for (int c = 0; c < NC; c++) {
    float a = A[lane][c];              // stride 65: conflict-free
    #pragma unroll
    for (int j = 0; j < 8; j++)
      acc[j] = fmaf(a, w_proj[c*64 + jb + j], acc[j]);
  }
  #pragma unroll
  for (int j = 0; j < 8; j++)
    out[(size_t)(jb + j) * PTOT + p0 + lane] = acc[j];
}

extern "C" void kernel_launch(void* const* d_in, const int* in_sizes, int n_in,
                              void* d_out, int out_size, void* d_ws, size_t ws_size,
                              hipStream_t stream) {
  const float* skip = (const float*)d_in[0];
  const float* up   = (const float*)d_in[1];
  const float* w_qk = (const float*)d_in[2];
  const float* b_qk = (const float*)d_in[3];
  const float* w_v  = (const float*)d_in[4];
  const float* b_v  = (const float*)d_in[5];
  const float* w_pr = (const float*)d_in[6];
  const float* b_pr = (const float*)d_in[7];
  const float* rpb  = (const float*)d_in[8];
  float* ws  = (float*)d_ws;
  float* out = (float*)d_out;

  k_stats<<<128, 1024, 0, stream>>>(skip, up, ws);
  k_qkv<<<dim3(512, 3), 256, 0, stream>>>(skip, up, w_qk, b_qk, w_v, b_v, ws);
  k_attn_proj<<<(PD*PH)/8, 512, 0, stream>>>(rpb, w_pr, b_pr, ws, out);
}